// Round 22
// baseline (188.091 us; speedup 1.0000x reference)
//
#include <hip/hip_runtime.h>
#include <math.h>

#define FEAT 64
#define BN_EPS 1e-5f
#define BN_REPS 64   // R11: 16 reps -> 4x same-address atomic depth -> +65us.
#define CNT_REPS 4   // replicated edge-count histogram: atomic line depth /4

__device__ __forceinline__ int edge_idx(const void* p, int is64, long long i) {
    return is64 ? (int)((const long long*)p)[i] : ((const int*)p)[i];
}

__device__ __forceinline__ float4 f4fma(float a, float4 b, float4 c) {
    return make_float4(fmaf(a, b.x, c.x), fmaf(a, b.y, c.y),
                       fmaf(a, b.z, c.z), fmaf(a, b.w, c.w));
}

// bf16 pack (round-to-nearest-even) / unpack-as-bit-ops
__device__ __forceinline__ unsigned bf16rtne(float f) {
    unsigned u = __float_as_uint(f);
    return (u + 0x7fffu + ((u >> 16) & 1u)) >> 16;
}
__device__ __forceinline__ unsigned packbf2(float a, float b) {
    return bf16rtne(a) | (bf16rtne(b) << 16);
}
__device__ __forceinline__ float4 unpackbf4(uint2 r) {
    return make_float4(__uint_as_float(r.x << 16),
                       __uint_as_float(r.x & 0xffff0000u),
                       __uint_as_float(r.y << 16),
                       __uint_as_float(r.y & 0xffff0000u));
}

// ---------------------------------------------------------------------------
// init: cnt[0..4N)=0; first 64 blocks zero BN partial buckets; block 0
// detects edge_index dtype (int64 high words all 0).
// ---------------------------------------------------------------------------
__global__ __launch_bounds__(256) void init_kernel(
    const unsigned* __restrict__ w, int* __restrict__ flag,
    int* __restrict__ cnt, float* __restrict__ parts, int N4) {
    int i = blockIdx.x * 256 + threadIdx.x;
    if (i < N4) cnt[i] = 0;
    if (blockIdx.x < 64) parts[blockIdx.x * 256 + threadIdx.x] = 0.0f;
    if (blockIdx.x == 0 && threadIdx.x < 64) {
        unsigned long long ok = __ballot(w[2 * threadIdx.x + 1] == 0u);
        if (threadIdx.x == 0) *flag = (ok == ~0ull);
    }
}

// ---------------------------------------------------------------------------
// FAT kernel: blocks [0,nc) run count_seq into 4 replica histograms
// (replica r = e&3); blocks [nc,nc+ng) run layer-1 GEMM.
// ---------------------------------------------------------------------------
__global__ __launch_bounds__(256) void fused_count_gemm1_kernel(
    const void* __restrict__ ei, const int* __restrict__ flag,
    int* __restrict__ cnt, int* __restrict__ seq, int E,
    const float* __restrict__ x, const float* __restrict__ W1,
    uint2* __restrict__ out_bf, int N, int nc) {
    __shared__ float4 Ws4[64][16];
    __shared__ float xs[64][65];
    int tid = threadIdx.x;

    if ((int)blockIdx.x < nc) {
        // ---- count_seq branch: 8 independent atomics per thread ----
        int is64 = *flag;
        int T = nc * 256;
        int i = blockIdx.x * 256 + tid;
#pragma unroll
        for (int u = 0; u < 8; ++u) {
            int e = i + u * T;
            if (e < E) {
                int dst = edge_idx(ei, is64, (long long)E + e);
                seq[e] = atomicAdd(&cnt[(e & 3) * N + dst], 1);
            }
        }
        return;
    }

    // ---- gemm1 branch ----
    int gb = blockIdx.x - nc;
    const float4* W4 = (const float4*)W1;
    for (int j = tid; j < 1024; j += 256) Ws4[j >> 4][j & 15] = W4[j];
    __syncthreads();

    int rowBase = gb * 64;
    for (int j = tid; j < 1024; j += 256) {
        int r = j >> 4, q = j & 15;
        int row = rowBase + r;
        float4 v = make_float4(0.f, 0.f, 0.f, 0.f);
        if (row < N) v = ((const float4*)x)[(size_t)row * 16 + q];
        xs[r][q * 4 + 0] = v.x;
        xs[r][q * 4 + 1] = v.y;
        xs[r][q * 4 + 2] = v.z;
        xs[r][q * 4 + 3] = v.w;
    }
    __syncthreads();

    int q = tid & 15, rg = tid >> 4;
    int r0 = rg * 4;
    float4 a0 = make_float4(0.f, 0.f, 0.f, 0.f), a1 = a0, a2 = a0, a3 = a0;
#pragma unroll 4
    for (int k = 0; k < 64; ++k) {
        float4 wv = Ws4[k][q];
        a0 = f4fma(xs[r0 + 0][k], wv, a0);
        a1 = f4fma(xs[r0 + 1][k], wv, a1);
        a2 = f4fma(xs[r0 + 2][k], wv, a2);
        a3 = f4fma(xs[r0 + 3][k], wv, a3);
    }
    int row = rowBase + r0;
    if (row + 0 < N) out_bf[(size_t)(row + 0) * 16 + q] = make_uint2(packbf2(a0.x, a0.y), packbf2(a0.z, a0.w));
    if (row + 1 < N) out_bf[(size_t)(row + 1) * 16 + q] = make_uint2(packbf2(a1.x, a1.y), packbf2(a1.z, a1.w));
    if (row + 2 < N) out_bf[(size_t)(row + 2) * 16 + q] = make_uint2(packbf2(a2.x, a2.y), packbf2(a2.z, a2.w));
    if (row + 3 < N) out_bf[(size_t)(row + 3) * 16 + q] = make_uint2(packbf2(a3.x, a3.y), packbf2(a3.z, a3.w));
}

// ---- scan over 4N bucket counts, order j = 4*node + replica ---------------
__global__ __launch_bounds__(256) void scan1_kernel(const int* __restrict__ cnt,
                                                    int* __restrict__ excl,
                                                    int* __restrict__ bsum,
                                                    int N, int N4) {
    __shared__ int tmp[256];
    int j = blockIdx.x * 256 + threadIdx.x;
    int v = (j < N4) ? cnt[(j & 3) * N + (j >> 2)] : 0;
    tmp[threadIdx.x] = v;
    __syncthreads();
    for (int off = 1; off < 256; off <<= 1) {
        int t = (threadIdx.x >= off) ? tmp[threadIdx.x - off] : 0;
        __syncthreads();
        tmp[threadIdx.x] += t;
        __syncthreads();
    }
    if (j < N4) excl[j] = tmp[threadIdx.x] - v;
    if (threadIdx.x == 255) bsum[blockIdx.x] = tmp[255];
}

// rptrR[j] = excl[j] + prefix(bsum); each block self-computes its prefix.
__global__ __launch_bounds__(256) void scan3_kernel(const int* __restrict__ excl,
                                                    const int* __restrict__ bsum,
                                                    int* __restrict__ rptrR,
                                                    int N4, int E, int nb) {
    __shared__ int red[256];
    int tid = threadIdx.x;
    int s = 0;
#pragma unroll
    for (int k = tid; k < 1024; k += 256)
        if (k < nb && k < (int)blockIdx.x) s += bsum[k];
    red[tid] = s;
    __syncthreads();
    for (int off = 128; off > 0; off >>= 1) {
        if (tid < off) red[tid] += red[tid + off];
        __syncthreads();
    }
    int base = red[0];
    int j = blockIdx.x * 256 + tid;
    if (j < N4) rptrR[j] = excl[j] + base;
    if (blockIdx.x == 0 && tid == 0) rptrR[N4] = E;
}

// csr[rptrR[dst*4 + (e&3)] + seq[e]] = src(u16) | bf16(ew)<<16  (raw ew)
__global__ __launch_bounds__(256) void scatter_csr_kernel(
    const void* __restrict__ ei, const float* __restrict__ ew,
    const int* __restrict__ flag, const int* __restrict__ rptrR,
    const int* __restrict__ seq, unsigned* __restrict__ csr, int E) {
    int is64 = *flag;
    int T = gridDim.x * 256;
    int i = blockIdx.x * 256 + threadIdx.x;
#pragma unroll
    for (int u = 0; u < 2; ++u) {
        int e = i + u * T;
        if (e < E) {
            int src = edge_idx(ei, is64, e);
            int dst = edge_idx(ei, is64, (long long)E + e);
            int pos = rptrR[(dst << 2) | (e & 3)] + seq[e];
            csr[pos] = (unsigned)src | (bf16rtne(ew[e]) << 16);
        }
    }
}

// ---------------------------------------------------------------------------
// deg_inv_scale: phase A computes dinv[n]=rsqrt(1+sum ew) (8 lanes/node,
// 32 nodes/block); phase B rescales this block's h rows in place:
// h'[n] = bf16(dinv[n] * h[n]).
// ---------------------------------------------------------------------------
__global__ __launch_bounds__(256) void deg_inv_scale_kernel(
    const int* __restrict__ rptrR, const unsigned* __restrict__ csr,
    float* __restrict__ dinv, uint2* __restrict__ h_bf, int N) {
    __shared__ float sd[32];
    int tid = threadIdx.x;
    int n = blockIdx.x * 32 + (tid >> 3), l = tid & 7;
    if (n < N) {
        int b = rptrR[n << 2], e = rptrR[(n << 2) + 4];
        float d = 0.0f;
        for (int k = b + l; k < e; k += 8)
            d += __uint_as_float(csr[k] & 0xffff0000u);
        d += __shfl_xor(d, 1);
        d += __shfl_xor(d, 2);
        d += __shfl_xor(d, 4);
        if (l == 0) {
            float dv = rsqrtf(1.0f + d);
            dinv[n] = dv;
            sd[tid >> 3] = dv;
        }
    }
    __syncthreads();
    int rg = tid >> 4, sl = tid & 15;
#pragma unroll
    for (int p = 0; p < 2; ++p) {
        int m = p * 16 + rg;
        int row = blockIdx.x * 32 + m;
        if (row < N) {
            float dv = sd[m];
            size_t idx = (size_t)row * 16 + sl;
            float4 v = unpackbf4(h_bf[idx]);
            h_bf[idx] = make_uint2(packbf2(dv * v.x, dv * v.y),
                                   packbf2(dv * v.z, dv * v.w));
        }
    }
}

// ---------------------------------------------------------------------------
// Layer-2 GEMM, bf16 input (layer-1 agg), BN1 fused; epilogue scales by
// dinv[row] before bf16 pack (produces h' directly for gather2).
// ---------------------------------------------------------------------------
__global__ __launch_bounds__(256) void gemm2_kernel(
    const uint2* __restrict__ in_bf, const float* __restrict__ W,
    const float* __restrict__ parts, const float* __restrict__ gamma,
    const float* __restrict__ beta, const float* __restrict__ dinv,
    uint2* __restrict__ out_bf, int N, float invN) {
    __shared__ float4 Ws4[64][16];
    __shared__ float xs[64][65];
    __shared__ float sA[64], sS[64];
    int tid = threadIdx.x;
    const float4* W4 = (const float4*)W;
    for (int j = tid; j < 1024; j += 256) Ws4[j >> 4][j & 15] = W4[j];
    if (tid < 64) {
        float sm = 0.f, sq = 0.f;
#pragma unroll
        for (int r = 0; r < BN_REPS; ++r) {
            sm += parts[r * 128 + tid];
            sq += parts[r * 128 + 64 + tid];
        }
        float m = sm * invN;
        float var = fmaxf(sq * invN - m * m, 0.0f);
        float aa = gamma[tid] * rsqrtf(var + BN_EPS);
        sA[tid] = aa;
        sS[tid] = beta[tid] - m * aa;
    }
    __syncthreads();

    int rowBase = blockIdx.x * 64;
    for (int j = tid; j < 1024; j += 256) {
        int r = j >> 4, q = j & 15;
        int row = rowBase + r;
        float4 v = make_float4(0.f, 0.f, 0.f, 0.f);
        if (row < N) {
            v = unpackbf4(in_bf[(size_t)row * 16 + q]);
            int c = q * 4;
            v.x = fmaxf(fmaf(v.x, sA[c + 0], sS[c + 0]), 0.f);
            v.y = fmaxf(fmaf(v.y, sA[c + 1], sS[c + 1]), 0.f);
            v.z = fmaxf(fmaf(v.z, sA[c + 2], sS[c + 2]), 0.f);
            v.w = fmaxf(fmaf(v.w, sA[c + 3], sS[c + 3]), 0.f);
        }
        xs[r][q * 4 + 0] = v.x;
        xs[r][q * 4 + 1] = v.y;
        xs[r][q * 4 + 2] = v.z;
        xs[r][q * 4 + 3] = v.w;
    }
    __syncthreads();

    int q = tid & 15, rg = tid >> 4;
    int r0 = rg * 4;
    float4 a0 = make_float4(0.f, 0.f, 0.f, 0.f), a1 = a0, a2 = a0, a3 = a0;
#pragma unroll 4
    for (int k = 0; k < 64; ++k) {
        float4 wv = Ws4[k][q];
        a0 = f4fma(xs[r0 + 0][k], wv, a0);
        a1 = f4fma(xs[r0 + 1][k], wv, a1);
        a2 = f4fma(xs[r0 + 2][k], wv, a2);
        a3 = f4fma(xs[r0 + 3][k], wv, a3);
    }
    int row = rowBase + r0;
    if (row + 0 < N) { float d = dinv[row + 0]; out_bf[(size_t)(row + 0) * 16 + q] = make_uint2(packbf2(d * a0.x, d * a0.y), packbf2(d * a0.z, d * a0.w)); }
    if (row + 1 < N) { float d = dinv[row + 1]; out_bf[(size_t)(row + 1) * 16 + q] = make_uint2(packbf2(d * a1.x, d * a1.y), packbf2(d * a1.z, d * a1.w)); }
    if (row + 2 < N) { float d = dinv[row + 2]; out_bf[(size_t)(row + 2) * 16 + q] = make_uint2(packbf2(d * a2.x, d * a2.y), packbf2(d * a2.z, d * a2.w)); }
    if (row + 3 < N) { float d = dinv[row + 3]; out_bf[(size_t)(row + 3) * 16 + q] = make_uint2(packbf2(d * a3.x, d * a3.y), packbf2(d * a3.z, d * a3.w)); }
}

// ---------------------------------------------------------------------------
// agg[n] = dinv[n]*(sum_k ew_k*h'[src[k]] + h'[n]) + bias   (h' = dinv*h)
// + fused BN column stats -> 64-replica atomic buckets.
// 8 nodes per wave (R22): BN partials span 8 nodes in registers -> tail
// atomics & write traffic /2 vs R21. Per node: 32-edge chunks, 8-deep
// bursts, 4B packed csr. Output bf16 for BOTH layers.
// ---------------------------------------------------------------------------
__global__ __launch_bounds__(256) void gather_agg_kernel(
    const uint2* __restrict__ h2, const int* __restrict__ rptrR,
    const unsigned* __restrict__ csr, const float* __restrict__ dinv,
    const float* __restrict__ bias,
    uint2* __restrict__ aggout, float* __restrict__ parts, int N) {
    int tid = threadIdx.x;
    int wave = tid >> 6, lane = tid & 63;
    int sub = lane >> 4, sl = lane & 15;
    float4 bv = ((const float4*)bias)[sl];
    float4 bnS = make_float4(0.f, 0.f, 0.f, 0.f), bnQ = bnS;

    int n0 = blockIdx.x * 32 + wave * 8;   // 8 nodes per wave
#pragma unroll
    for (int i = 0; i < 8; ++i) {
        int n = n0 + i;
        if (n >= N) break;
        int beg = rptrR[n << 2], end = rptrR[(n << 2) + 4];
        uint2 selfr = h2[(size_t)n * 16 + sl];   // early independent load
        float dn = dinv[n];

        float4 accE = make_float4(0.f, 0.f, 0.f, 0.f);
        for (int k = beg; k < end; k += 32) {
            int srcs[8]; float w[8];
#pragma unroll
            for (int j = 0; j < 8; ++j) {        // burst 1: packed csr (nt)
                int idx = k + sub + 4 * j;       // subgroup-uniform predicate
                if (idx < end) {
                    unsigned v = __builtin_nontemporal_load(&csr[idx]);
                    srcs[j] = (int)(v & 0xffffu);
                    w[j] = __uint_as_float(v & 0xffff0000u);
                } else { srcs[j] = 0; w[j] = 0.f; }
            }
            uint2 hr[8];
#pragma unroll
            for (int j = 0; j < 8; ++j)          // burst 2: h rows (8B/lane)
                hr[j] = (k + sub + 4 * j < end)
                          ? h2[(size_t)srcs[j] * 16 + sl] : make_uint2(0u, 0u);
#pragma unroll
            for (int j = 0; j < 8; ++j)          // burst 3: fma
                accE = f4fma(w[j], unpackbf4(hr[j]), accE);
        }
        // combine the 4 subgroup partials (xor over lane bits 4,5)
        accE.x += __shfl_xor(accE.x, 16); accE.y += __shfl_xor(accE.y, 16);
        accE.z += __shfl_xor(accE.z, 16); accE.w += __shfl_xor(accE.w, 16);
        accE.x += __shfl_xor(accE.x, 32); accE.y += __shfl_xor(accE.y, 32);
        accE.z += __shfl_xor(accE.z, 32); accE.w += __shfl_xor(accE.w, 32);

        if (sub == 0) {
            float4 self = unpackbf4(selfr);
            float4 tot;   // dn*(accE + self) + bias
            tot.x = fmaf(dn, accE.x + self.x, bv.x);
            tot.y = fmaf(dn, accE.y + self.y, bv.y);
            tot.z = fmaf(dn, accE.z + self.z, bv.z);
            tot.w = fmaf(dn, accE.w + self.w, bv.w);
            aggout[(size_t)n * 16 + sl] =
                make_uint2(packbf2(tot.x, tot.y), packbf2(tot.z, tot.w));
            bnS.x += tot.x; bnS.y += tot.y; bnS.z += tot.z; bnS.w += tot.w;
            bnQ.x = fmaf(tot.x, tot.x, bnQ.x); bnQ.y = fmaf(tot.y, tot.y, bnQ.y);
            bnQ.z = fmaf(tot.z, tot.z, bnQ.z); bnQ.w = fmaf(tot.w, tot.w, bnQ.w);
        }
    }

    __shared__ float4 LS[4][16], LQ[4][16];
    if (sub == 0) { LS[wave][sl] = bnS; LQ[wave][sl] = bnQ; }
    __syncthreads();
    if (tid < 16) {
        float4 ts = LS[0][tid], tq = LQ[0][tid];
        for (int i = 1; i < 4; ++i) {
            float4 a = LS[i][tid], b = LQ[i][tid];
            ts.x += a.x; ts.y += a.y; ts.z += a.z; ts.w += a.w;
            tq.x += b.x; tq.y += b.y; tq.z += b.z; tq.w += b.w;
        }
        // replica bucket: [rep][ sum[64] | sq[64] ]
        float* P = parts + (size_t)(blockIdx.x & (BN_REPS - 1)) * 128;
        int c = tid * 4;
        unsafeAtomicAdd(&P[c + 0], ts.x);      unsafeAtomicAdd(&P[c + 1], ts.y);
        unsafeAtomicAdd(&P[c + 2], ts.z);      unsafeAtomicAdd(&P[c + 3], ts.w);
        unsafeAtomicAdd(&P[64 + c + 0], tq.x); unsafeAtomicAdd(&P[64 + c + 1], tq.y);
        unsafeAtomicAdd(&P[64 + c + 2], tq.z); unsafeAtomicAdd(&P[64 + c + 3], tq.w);
    }
}

// out = relu(agg*a2 + s2 + x); agg in bf16; BN2 finalize fused
__global__ __launch_bounds__(256) void final_out_kernel(
    const uint2* __restrict__ agg_bf, const float* __restrict__ parts,
    const float* __restrict__ gamma, const float* __restrict__ beta,
    const float* __restrict__ x, float* __restrict__ out,
    int nquads, float invN) {
    __shared__ float sA[64], sS[64];
    int tid = threadIdx.x;
    if (tid < 64) {
        float sm = 0.f, sq = 0.f;
#pragma unroll
        for (int r = 0; r < BN_REPS; ++r) {
            sm += parts[r * 128 + tid];
            sq += parts[r * 128 + 64 + tid];
        }
        float m = sm * invN;
        float var = fmaxf(sq * invN - m * m, 0.0f);
        float aa = gamma[tid] * rsqrtf(var + BN_EPS);
        sA[tid] = aa;
        sS[tid] = beta[tid] - m * aa;
    }
    __syncthreads();
    int gid = blockIdx.x * 256 + tid;
    if (gid < nquads) {
        int c = (gid & 15) * 4;
        float4 g = unpackbf4(agg_bf[gid]);
        float4 xv = ((const float4*)x)[gid];
        float4 o;
        o.x = fmaxf(fmaf(g.x, sA[c + 0], sS[c + 0]) + xv.x, 0.f);
        o.y = fmaxf(fmaf(g.y, sA[c + 1], sS[c + 1]) + xv.y, 0.f);
        o.z = fmaxf(fmaf(g.z, sA[c + 2], sS[c + 2]) + xv.z, 0.f);
        o.w = fmaxf(fmaf(g.w, sA[c + 3], sS[c + 3]) + xv.w, 0.f);
        ((float4*)out)[gid] = o;
    }
}

extern "C" void kernel_launch(void* const* d_in, const int* in_sizes, int n_in,
                              void* d_out, int out_size, void* d_ws, size_t ws_size,
                              hipStream_t stream) {
    const float* x      = (const float*)d_in[0];
    const void*  ei     = d_in[1];           // int64 or int32, detected on device
    const float* ew     = (const float*)d_in[2];
    const float* W1     = (const float*)d_in[3];
    const float* b1     = (const float*)d_in[4];
    const float* gamma1 = (const float*)d_in[5];
    const float* beta1  = (const float*)d_in[6];
    const float* W2     = (const float*)d_in[7];
    const float* b2     = (const float*)d_in[8];
    const float* gamma2 = (const float*)d_in[9];
    const float* beta2  = (const float*)d_in[10];
    float* out = (float*)d_out;

    const int N = in_sizes[0] / FEAT;
    const int E = in_sizes[2];
    const int N4 = N * CNT_REPS;

    // workspace layout (256B-aligned chunks)
    char* ws = (char*)d_ws;
    size_t off = 0;
    auto alloc = [&](size_t bytes) {
        size_t o = off;
        off += (bytes + 255) & ~(size_t)255;
        return (void*)(ws + o);
    };
    int*      flag   = (int*)     alloc(256);
    int*      cnt    = (int*)     alloc((size_t)N4 * 4);
    int*      rptrR  = (int*)     alloc((size_t)(N4 + 1) * 4);
    int*      seq    = (int*)     alloc((size_t)E * 4);
    int*      excl   = (int*)     alloc((size_t)N4 * 4);
    int*      bsum   = (int*)     alloc(1024 * 4);
    float*    dinv   = (float*)   alloc((size_t)N * 4);
    float*    parts  = (float*)   alloc(2 * BN_REPS * 128 * 4);
    unsigned* csr    = (unsigned*)alloc((size_t)E * 4);   // packed 4B/edge
    uint2*    h_bf   = (uint2*)   alloc((size_t)N * 16 * 8);  // N x 64 bf16
    uint2*    agg_bf = (uint2*)   alloc((size_t)N * 16 * 8);  // agg (both layers)

    const int nblkN4 = (N4 + 255) / 256;
    const int nblkE2 = (E + 511) / 512;
    const int nblkQ  = (N * 16 + 255) / 256;
    const int nblkG  = (N + 63) / 64;
    const int nblkA  = (N + 31) / 32;      // 4 waves x 8 nodes per block
    const int nblkD  = (N + 31) / 32;      // deg_inv_scale: 32 nodes/block
    const int nc     = (E + 2047) / 2048;  // count blocks: 8 edges/thread
    const float invN = 1.0f / (float)N;

    // ---- CSR build + layer-1 GEMM (overlapped) ----
    init_kernel<<<nblkN4, 256, 0, stream>>>((const unsigned*)ei, flag, cnt, parts, N4);
    fused_count_gemm1_kernel<<<nc + nblkG, 256, 0, stream>>>(
        ei, flag, cnt, seq, E, x, W1, h_bf, N, nc);
    scan1_kernel<<<nblkN4, 256, 0, stream>>>(cnt, excl, bsum, N, N4);
    scan3_kernel<<<nblkN4, 256, 0, stream>>>(excl, bsum, rptrR, N4, E, nblkN4);
    scatter_csr_kernel<<<nblkE2, 256, 0, stream>>>(ei, ew, flag, rptrR, seq, csr, E);
    deg_inv_scale_kernel<<<nblkD, 256, 0, stream>>>(rptrR, csr, dinv, h_bf, N);

    // ---- layer 1 gather (+BN1 stats; bf16 agg out) ----
    gather_agg_kernel<<<nblkA, 256, 0, stream>>>(h_bf, rptrR, csr, dinv,
                                                 b1, agg_bf, parts, N);
    // ---- layer 2 GEMM (bf16 in; BN1 finalize+apply+relu; dinv-scaled out) --
    gemm2_kernel<<<nblkG, 256, 0, stream>>>(agg_bf, W2, parts, gamma1, beta1,
                                            dinv, h_bf, N, invN);
    // ---- layer 2 gather (+BN2 stats; bf16 agg out, reuses agg_bf) ----
    gather_agg_kernel<<<nblkA, 256, 0, stream>>>(h_bf, rptrR, csr, dinv,
                                                 b2, agg_bf,
                                                 parts + BN_REPS * 128, N);
    // ---- BN2 finalize + residual + relu ----
    final_out_kernel<<<nblkQ, 256, 0, stream>>>(agg_bf, parts + BN_REPS * 128,
                                                gamma2, beta2, x, out,
                                                N * 16, invN);
}

// Round 23
// 176.513 us; speedup vs baseline: 1.0656x; 1.0656x over previous
//
#include <hip/hip_runtime.h>
#include <math.h>

#define FEAT 64
#define BN_EPS 1e-5f
#define BN_REPS 64   // R11: 16 reps -> 4x same-address atomic depth -> +65us.
#define CNT_REPS 4   // replicated edge-count histogram: atomic line depth /4

__device__ __forceinline__ int edge_idx(const void* p, int is64, long long i) {
    return is64 ? (int)((const long long*)p)[i] : ((const int*)p)[i];
}

__device__ __forceinline__ float4 f4fma(float a, float4 b, float4 c) {
    return make_float4(fmaf(a, b.x, c.x), fmaf(a, b.y, c.y),
                       fmaf(a, b.z, c.z), fmaf(a, b.w, c.w));
}

// bf16 pack (round-to-nearest-even) / unpack-as-bit-ops
__device__ __forceinline__ unsigned bf16rtne(float f) {
    unsigned u = __float_as_uint(f);
    return (u + 0x7fffu + ((u >> 16) & 1u)) >> 16;
}
__device__ __forceinline__ unsigned packbf2(float a, float b) {
    return bf16rtne(a) | (bf16rtne(b) << 16);
}
__device__ __forceinline__ float4 unpackbf4(uint2 r) {
    return make_float4(__uint_as_float(r.x << 16),
                       __uint_as_float(r.x & 0xffff0000u),
                       __uint_as_float(r.y << 16),
                       __uint_as_float(r.y & 0xffff0000u));
}

// ---------------------------------------------------------------------------
// init: cnt[0..4N)=0; first 64 blocks zero BN partial buckets; block 0
// detects edge_index dtype (int64 high words all 0).
// ---------------------------------------------------------------------------
__global__ __launch_bounds__(256) void init_kernel(
    const unsigned* __restrict__ w, int* __restrict__ flag,
    int* __restrict__ cnt, float* __restrict__ parts, int N4) {
    int i = blockIdx.x * 256 + threadIdx.x;
    if (i < N4) cnt[i] = 0;
    if (blockIdx.x < 64) parts[blockIdx.x * 256 + threadIdx.x] = 0.0f;
    if (blockIdx.x == 0 && threadIdx.x < 64) {
        unsigned long long ok = __ballot(w[2 * threadIdx.x + 1] == 0u);
        if (threadIdx.x == 0) *flag = (ok == ~0ull);
    }
}

// ---------------------------------------------------------------------------
// FAT kernel: blocks [0,nc) run count_seq into 4 replica histograms
// (replica r = e&3); blocks [nc,nc+ng) run layer-1 GEMM.
// ---------------------------------------------------------------------------
__global__ __launch_bounds__(256) void fused_count_gemm1_kernel(
    const void* __restrict__ ei, const int* __restrict__ flag,
    int* __restrict__ cnt, int* __restrict__ seq, int E,
    const float* __restrict__ x, const float* __restrict__ W1,
    uint2* __restrict__ out_bf, int N, int nc) {
    __shared__ float4 Ws4[64][16];
    __shared__ float xs[64][65];
    int tid = threadIdx.x;

    if ((int)blockIdx.x < nc) {
        // ---- count_seq branch: 8 independent atomics per thread ----
        int is64 = *flag;
        int T = nc * 256;
        int i = blockIdx.x * 256 + tid;
#pragma unroll
        for (int u = 0; u < 8; ++u) {
            int e = i + u * T;
            if (e < E) {
                int dst = edge_idx(ei, is64, (long long)E + e);
                seq[e] = atomicAdd(&cnt[(e & 3) * N + dst], 1);
            }
        }
        return;
    }

    // ---- gemm1 branch ----
    int gb = blockIdx.x - nc;
    const float4* W4 = (const float4*)W1;
    for (int j = tid; j < 1024; j += 256) Ws4[j >> 4][j & 15] = W4[j];
    __syncthreads();

    int rowBase = gb * 64;
    for (int j = tid; j < 1024; j += 256) {
        int r = j >> 4, q = j & 15;
        int row = rowBase + r;
        float4 v = make_float4(0.f, 0.f, 0.f, 0.f);
        if (row < N) v = ((const float4*)x)[(size_t)row * 16 + q];
        xs[r][q * 4 + 0] = v.x;
        xs[r][q * 4 + 1] = v.y;
        xs[r][q * 4 + 2] = v.z;
        xs[r][q * 4 + 3] = v.w;
    }
    __syncthreads();

    int q = tid & 15, rg = tid >> 4;
    int r0 = rg * 4;
    float4 a0 = make_float4(0.f, 0.f, 0.f, 0.f), a1 = a0, a2 = a0, a3 = a0;
#pragma unroll 4
    for (int k = 0; k < 64; ++k) {
        float4 wv = Ws4[k][q];
        a0 = f4fma(xs[r0 + 0][k], wv, a0);
        a1 = f4fma(xs[r0 + 1][k], wv, a1);
        a2 = f4fma(xs[r0 + 2][k], wv, a2);
        a3 = f4fma(xs[r0 + 3][k], wv, a3);
    }
    int row = rowBase + r0;
    if (row + 0 < N) out_bf[(size_t)(row + 0) * 16 + q] = make_uint2(packbf2(a0.x, a0.y), packbf2(a0.z, a0.w));
    if (row + 1 < N) out_bf[(size_t)(row + 1) * 16 + q] = make_uint2(packbf2(a1.x, a1.y), packbf2(a1.z, a1.w));
    if (row + 2 < N) out_bf[(size_t)(row + 2) * 16 + q] = make_uint2(packbf2(a2.x, a2.y), packbf2(a2.z, a2.w));
    if (row + 3 < N) out_bf[(size_t)(row + 3) * 16 + q] = make_uint2(packbf2(a3.x, a3.y), packbf2(a3.z, a3.w));
}

// ---- scan over 4N bucket counts, order j = 4*node + replica ---------------
__global__ __launch_bounds__(256) void scan1_kernel(const int* __restrict__ cnt,
                                                    int* __restrict__ excl,
                                                    int* __restrict__ bsum,
                                                    int N, int N4) {
    __shared__ int tmp[256];
    int j = blockIdx.x * 256 + threadIdx.x;
    int v = (j < N4) ? cnt[(j & 3) * N + (j >> 2)] : 0;
    tmp[threadIdx.x] = v;
    __syncthreads();
    for (int off = 1; off < 256; off <<= 1) {
        int t = (threadIdx.x >= off) ? tmp[threadIdx.x - off] : 0;
        __syncthreads();
        tmp[threadIdx.x] += t;
        __syncthreads();
    }
    if (j < N4) excl[j] = tmp[threadIdx.x] - v;
    if (threadIdx.x == 255) bsum[blockIdx.x] = tmp[255];
}

// rptrR[j] = excl[j] + prefix(bsum); each block self-computes its prefix.
__global__ __launch_bounds__(256) void scan3_kernel(const int* __restrict__ excl,
                                                    const int* __restrict__ bsum,
                                                    int* __restrict__ rptrR,
                                                    int N4, int E, int nb) {
    __shared__ int red[256];
    int tid = threadIdx.x;
    int s = 0;
#pragma unroll
    for (int k = tid; k < 1024; k += 256)
        if (k < nb && k < (int)blockIdx.x) s += bsum[k];
    red[tid] = s;
    __syncthreads();
    for (int off = 128; off > 0; off >>= 1) {
        if (tid < off) red[tid] += red[tid + off];
        __syncthreads();
    }
    int base = red[0];
    int j = blockIdx.x * 256 + tid;
    if (j < N4) rptrR[j] = excl[j] + base;
    if (blockIdx.x == 0 && tid == 0) rptrR[N4] = E;
}

// csr[rptrR[dst*4 + (e&3)] + seq[e]] = src(u16) | bf16(ew)<<16  (raw ew)
__global__ __launch_bounds__(256) void scatter_csr_kernel(
    const void* __restrict__ ei, const float* __restrict__ ew,
    const int* __restrict__ flag, const int* __restrict__ rptrR,
    const int* __restrict__ seq, unsigned* __restrict__ csr, int E) {
    int is64 = *flag;
    int T = gridDim.x * 256;
    int i = blockIdx.x * 256 + threadIdx.x;
#pragma unroll
    for (int u = 0; u < 2; ++u) {
        int e = i + u * T;
        if (e < E) {
            int src = edge_idx(ei, is64, e);
            int dst = edge_idx(ei, is64, (long long)E + e);
            int pos = rptrR[(dst << 2) | (e & 3)] + seq[e];
            csr[pos] = (unsigned)src | (bf16rtne(ew[e]) << 16);
        }
    }
}

// ---------------------------------------------------------------------------
// deg_inv_scale: phase A computes dinv[n]=rsqrt(1+sum ew) (8 lanes/node,
// 32 nodes/block); phase B rescales this block's h rows in place:
// h'[n] = bf16(dinv[n] * h[n]).
// ---------------------------------------------------------------------------
__global__ __launch_bounds__(256) void deg_inv_scale_kernel(
    const int* __restrict__ rptrR, const unsigned* __restrict__ csr,
    float* __restrict__ dinv, uint2* __restrict__ h_bf, int N) {
    __shared__ float sd[32];
    int tid = threadIdx.x;
    int n = blockIdx.x * 32 + (tid >> 3), l = tid & 7;
    if (n < N) {
        int b = rptrR[n << 2], e = rptrR[(n << 2) + 4];
        float d = 0.0f;
        for (int k = b + l; k < e; k += 8)
            d += __uint_as_float(csr[k] & 0xffff0000u);
        d += __shfl_xor(d, 1);
        d += __shfl_xor(d, 2);
        d += __shfl_xor(d, 4);
        if (l == 0) {
            float dv = rsqrtf(1.0f + d);
            dinv[n] = dv;
            sd[tid >> 3] = dv;
        }
    }
    __syncthreads();
    int rg = tid >> 4, sl = tid & 15;
#pragma unroll
    for (int p = 0; p < 2; ++p) {
        int m = p * 16 + rg;
        int row = blockIdx.x * 32 + m;
        if (row < N) {
            float dv = sd[m];
            size_t idx = (size_t)row * 16 + sl;
            float4 v = unpackbf4(h_bf[idx]);
            h_bf[idx] = make_uint2(packbf2(dv * v.x, dv * v.y),
                                   packbf2(dv * v.z, dv * v.w));
        }
    }
}

// ---------------------------------------------------------------------------
// Layer-2 GEMM, bf16 input (layer-1 agg), BN1 fused; epilogue scales by
// dinv[row] before bf16 pack (produces h' directly for gather2).
// ---------------------------------------------------------------------------
__global__ __launch_bounds__(256) void gemm2_kernel(
    const uint2* __restrict__ in_bf, const float* __restrict__ W,
    const float* __restrict__ parts, const float* __restrict__ gamma,
    const float* __restrict__ beta, const float* __restrict__ dinv,
    uint2* __restrict__ out_bf, int N, float invN) {
    __shared__ float4 Ws4[64][16];
    __shared__ float xs[64][65];
    __shared__ float sA[64], sS[64];
    int tid = threadIdx.x;
    const float4* W4 = (const float4*)W;
    for (int j = tid; j < 1024; j += 256) Ws4[j >> 4][j & 15] = W4[j];
    if (tid < 64) {
        float sm = 0.f, sq = 0.f;
#pragma unroll
        for (int r = 0; r < BN_REPS; ++r) {
            sm += parts[r * 128 + tid];
            sq += parts[r * 128 + 64 + tid];
        }
        float m = sm * invN;
        float var = fmaxf(sq * invN - m * m, 0.0f);
        float aa = gamma[tid] * rsqrtf(var + BN_EPS);
        sA[tid] = aa;
        sS[tid] = beta[tid] - m * aa;
    }
    __syncthreads();

    int rowBase = blockIdx.x * 64;
    for (int j = tid; j < 1024; j += 256) {
        int r = j >> 4, q = j & 15;
        int row = rowBase + r;
        float4 v = make_float4(0.f, 0.f, 0.f, 0.f);
        if (row < N) {
            v = unpackbf4(in_bf[(size_t)row * 16 + q]);
            int c = q * 4;
            v.x = fmaxf(fmaf(v.x, sA[c + 0], sS[c + 0]), 0.f);
            v.y = fmaxf(fmaf(v.y, sA[c + 1], sS[c + 1]), 0.f);
            v.z = fmaxf(fmaf(v.z, sA[c + 2], sS[c + 2]), 0.f);
            v.w = fmaxf(fmaf(v.w, sA[c + 3], sS[c + 3]), 0.f);
        }
        xs[r][q * 4 + 0] = v.x;
        xs[r][q * 4 + 1] = v.y;
        xs[r][q * 4 + 2] = v.z;
        xs[r][q * 4 + 3] = v.w;
    }
    __syncthreads();

    int q = tid & 15, rg = tid >> 4;
    int r0 = rg * 4;
    float4 a0 = make_float4(0.f, 0.f, 0.f, 0.f), a1 = a0, a2 = a0, a3 = a0;
#pragma unroll 4
    for (int k = 0; k < 64; ++k) {
        float4 wv = Ws4[k][q];
        a0 = f4fma(xs[r0 + 0][k], wv, a0);
        a1 = f4fma(xs[r0 + 1][k], wv, a1);
        a2 = f4fma(xs[r0 + 2][k], wv, a2);
        a3 = f4fma(xs[r0 + 3][k], wv, a3);
    }
    int row = rowBase + r0;
    if (row + 0 < N) { float d = dinv[row + 0]; out_bf[(size_t)(row + 0) * 16 + q] = make_uint2(packbf2(d * a0.x, d * a0.y), packbf2(d * a0.z, d * a0.w)); }
    if (row + 1 < N) { float d = dinv[row + 1]; out_bf[(size_t)(row + 1) * 16 + q] = make_uint2(packbf2(d * a1.x, d * a1.y), packbf2(d * a1.z, d * a1.w)); }
    if (row + 2 < N) { float d = dinv[row + 2]; out_bf[(size_t)(row + 2) * 16 + q] = make_uint2(packbf2(d * a2.x, d * a2.y), packbf2(d * a2.z, d * a2.w)); }
    if (row + 3 < N) { float d = dinv[row + 3]; out_bf[(size_t)(row + 3) * 16 + q] = make_uint2(packbf2(d * a3.x, d * a3.y), packbf2(d * a3.z, d * a3.w)); }
}

// ---------------------------------------------------------------------------
// agg[n] = dinv[n]*(sum_k ew_k*h'[src[k]] + h'[n]) + bias   (h' = dinv*h)
// + fused BN column stats -> 64-replica atomic buckets.
// R21-validated geometry: 4 nodes/wave (R22's 8/wave cut TLP and regressed);
// 32-edge chunks, 8-deep bursts, 4B packed csr. bf16 agg out (both layers).
// ---------------------------------------------------------------------------
__global__ __launch_bounds__(256) void gather_agg_kernel(
    const uint2* __restrict__ h2, const int* __restrict__ rptrR,
    const unsigned* __restrict__ csr, const float* __restrict__ dinv,
    const float* __restrict__ bias,
    uint2* __restrict__ aggout, float* __restrict__ parts, int N) {
    int tid = threadIdx.x;
    int wave = tid >> 6, lane = tid & 63;
    int sub = lane >> 4, sl = lane & 15;
    float4 bv = ((const float4*)bias)[sl];
    float4 bnS = make_float4(0.f, 0.f, 0.f, 0.f), bnQ = bnS;

    int n0 = blockIdx.x * 16 + wave * 4;   // 4 nodes per wave
#pragma unroll
    for (int i = 0; i < 4; ++i) {
        int n = n0 + i;
        if (n >= N) break;
        int beg = rptrR[n << 2], end = rptrR[(n << 2) + 4];
        uint2 selfr = h2[(size_t)n * 16 + sl];   // early independent load
        float dn = dinv[n];

        float4 accE = make_float4(0.f, 0.f, 0.f, 0.f);
        for (int k = beg; k < end; k += 32) {
            int srcs[8]; float w[8];
#pragma unroll
            for (int j = 0; j < 8; ++j) {        // burst 1: packed csr (nt)
                int idx = k + sub + 4 * j;       // subgroup-uniform predicate
                if (idx < end) {
                    unsigned v = __builtin_nontemporal_load(&csr[idx]);
                    srcs[j] = (int)(v & 0xffffu);
                    w[j] = __uint_as_float(v & 0xffff0000u);
                } else { srcs[j] = 0; w[j] = 0.f; }
            }
            uint2 hr[8];
#pragma unroll
            for (int j = 0; j < 8; ++j)          // burst 2: h rows (8B/lane)
                hr[j] = (k + sub + 4 * j < end)
                          ? h2[(size_t)srcs[j] * 16 + sl] : make_uint2(0u, 0u);
#pragma unroll
            for (int j = 0; j < 8; ++j)          // burst 3: fma
                accE = f4fma(w[j], unpackbf4(hr[j]), accE);
        }
        // combine the 4 subgroup partials (xor over lane bits 4,5)
        accE.x += __shfl_xor(accE.x, 16); accE.y += __shfl_xor(accE.y, 16);
        accE.z += __shfl_xor(accE.z, 16); accE.w += __shfl_xor(accE.w, 16);
        accE.x += __shfl_xor(accE.x, 32); accE.y += __shfl_xor(accE.y, 32);
        accE.z += __shfl_xor(accE.z, 32); accE.w += __shfl_xor(accE.w, 32);

        if (sub == 0) {
            float4 self = unpackbf4(selfr);
            float4 tot;   // dn*(accE + self) + bias
            tot.x = fmaf(dn, accE.x + self.x, bv.x);
            tot.y = fmaf(dn, accE.y + self.y, bv.y);
            tot.z = fmaf(dn, accE.z + self.z, bv.z);
            tot.w = fmaf(dn, accE.w + self.w, bv.w);
            aggout[(size_t)n * 16 + sl] =
                make_uint2(packbf2(tot.x, tot.y), packbf2(tot.z, tot.w));
            bnS.x += tot.x; bnS.y += tot.y; bnS.z += tot.z; bnS.w += tot.w;
            bnQ.x = fmaf(tot.x, tot.x, bnQ.x); bnQ.y = fmaf(tot.y, tot.y, bnQ.y);
            bnQ.z = fmaf(tot.z, tot.z, bnQ.z); bnQ.w = fmaf(tot.w, tot.w, bnQ.w);
        }
    }

    __shared__ float4 LS[4][16], LQ[4][16];
    if (sub == 0) { LS[wave][sl] = bnS; LQ[wave][sl] = bnQ; }
    __syncthreads();
    if (tid < 16) {
        float4 ts = LS[0][tid], tq = LQ[0][tid];
        for (int i = 1; i < 4; ++i) {
            float4 a = LS[i][tid], b = LQ[i][tid];
            ts.x += a.x; ts.y += a.y; ts.z += a.z; ts.w += a.w;
            tq.x += b.x; tq.y += b.y; tq.z += b.z; tq.w += b.w;
        }
        // replica bucket: [rep][ sum[64] | sq[64] ]
        float* P = parts + (size_t)(blockIdx.x & (BN_REPS - 1)) * 128;
        int c = tid * 4;
        unsafeAtomicAdd(&P[c + 0], ts.x);      unsafeAtomicAdd(&P[c + 1], ts.y);
        unsafeAtomicAdd(&P[c + 2], ts.z);      unsafeAtomicAdd(&P[c + 3], ts.w);
        unsafeAtomicAdd(&P[64 + c + 0], tq.x); unsafeAtomicAdd(&P[64 + c + 1], tq.y);
        unsafeAtomicAdd(&P[64 + c + 2], tq.z); unsafeAtomicAdd(&P[64 + c + 3], tq.w);
    }
}

// out = relu(agg*a2 + s2 + x); agg in bf16; BN2 finalize fused
__global__ __launch_bounds__(256) void final_out_kernel(
    const uint2* __restrict__ agg_bf, const float* __restrict__ parts,
    const float* __restrict__ gamma, const float* __restrict__ beta,
    const float* __restrict__ x, float* __restrict__ out,
    int nquads, float invN) {
    __shared__ float sA[64], sS[64];
    int tid = threadIdx.x;
    if (tid < 64) {
        float sm = 0.f, sq = 0.f;
#pragma unroll
        for (int r = 0; r < BN_REPS; ++r) {
            sm += parts[r * 128 + tid];
            sq += parts[r * 128 + 64 + tid];
        }
        float m = sm * invN;
        float var = fmaxf(sq * invN - m * m, 0.0f);
        float aa = gamma[tid] * rsqrtf(var + BN_EPS);
        sA[tid] = aa;
        sS[tid] = beta[tid] - m * aa;
    }
    __syncthreads();
    int gid = blockIdx.x * 256 + tid;
    if (gid < nquads) {
        int c = (gid & 15) * 4;
        float4 g = unpackbf4(agg_bf[gid]);
        float4 xv = ((const float4*)x)[gid];
        float4 o;
        o.x = fmaxf(fmaf(g.x, sA[c + 0], sS[c + 0]) + xv.x, 0.f);
        o.y = fmaxf(fmaf(g.y, sA[c + 1], sS[c + 1]) + xv.y, 0.f);
        o.z = fmaxf(fmaf(g.z, sA[c + 2], sS[c + 2]) + xv.z, 0.f);
        o.w = fmaxf(fmaf(g.w, sA[c + 3], sS[c + 3]) + xv.w, 0.f);
        ((float4*)out)[gid] = o;
    }
}

extern "C" void kernel_launch(void* const* d_in, const int* in_sizes, int n_in,
                              void* d_out, int out_size, void* d_ws, size_t ws_size,
                              hipStream_t stream) {
    const float* x      = (const float*)d_in[0];
    const void*  ei     = d_in[1];           // int64 or int32, detected on device
    const float* ew     = (const float*)d_in[2];
    const float* W1     = (const float*)d_in[3];
    const float* b1     = (const float*)d_in[4];
    const float* gamma1 = (const float*)d_in[5];
    const float* beta1  = (const float*)d_in[6];
    const float* W2     = (const float*)d_in[7];
    const float* b2     = (const float*)d_in[8];
    const float* gamma2 = (const float*)d_in[9];
    const float* beta2  = (const float*)d_in[10];
    float* out = (float*)d_out;

    const int N = in_sizes[0] / FEAT;
    const int E = in_sizes[2];
    const int N4 = N * CNT_REPS;

    // workspace layout (256B-aligned chunks)
    char* ws = (char*)d_ws;
    size_t off = 0;
    auto alloc = [&](size_t bytes) {
        size_t o = off;
        off += (bytes + 255) & ~(size_t)255;
        return (void*)(ws + o);
    };
    int*      flag   = (int*)     alloc(256);
    int*      cnt    = (int*)     alloc((size_t)N4 * 4);
    int*      rptrR  = (int*)     alloc((size_t)(N4 + 1) * 4);
    int*      seq    = (int*)     alloc((size_t)E * 4);
    int*      excl   = (int*)     alloc((size_t)N4 * 4);
    int*      bsum   = (int*)     alloc(1024 * 4);
    float*    dinv   = (float*)   alloc((size_t)N * 4);
    float*    parts  = (float*)   alloc(2 * BN_REPS * 128 * 4);
    unsigned* csr    = (unsigned*)alloc((size_t)E * 4);   // packed 4B/edge
    uint2*    h_bf   = (uint2*)   alloc((size_t)N * 16 * 8);  // N x 64 bf16
    uint2*    agg_bf = (uint2*)   alloc((size_t)N * 16 * 8);  // agg (both layers)

    const int nblkN4 = (N4 + 255) / 256;
    const int nblkE2 = (E + 511) / 512;
    const int nblkQ  = (N * 16 + 255) / 256;
    const int nblkG  = (N + 63) / 64;
    const int nblkA  = (N + 15) / 16;      // 4 waves x 4 nodes per block
    const int nblkD  = (N + 31) / 32;      // deg_inv_scale: 32 nodes/block
    const int nc     = (E + 2047) / 2048;  // count blocks: 8 edges/thread
    const float invN = 1.0f / (float)N;

    // ---- CSR build + layer-1 GEMM (overlapped) ----
    init_kernel<<<nblkN4, 256, 0, stream>>>((const unsigned*)ei, flag, cnt, parts, N4);
    fused_count_gemm1_kernel<<<nc + nblkG, 256, 0, stream>>>(
        ei, flag, cnt, seq, E, x, W1, h_bf, N, nc);
    scan1_kernel<<<nblkN4, 256, 0, stream>>>(cnt, excl, bsum, N, N4);
    scan3_kernel<<<nblkN4, 256, 0, stream>>>(excl, bsum, rptrR, N4, E, nblkN4);
    scatter_csr_kernel<<<nblkE2, 256, 0, stream>>>(ei, ew, flag, rptrR, seq, csr, E);
    deg_inv_scale_kernel<<<nblkD, 256, 0, stream>>>(rptrR, csr, dinv, h_bf, N);

    // ---- layer 1 gather (+BN1 stats; bf16 agg out) ----
    gather_agg_kernel<<<nblkA, 256, 0, stream>>>(h_bf, rptrR, csr, dinv,
                                                 b1, agg_bf, parts, N);
    // ---- layer 2 GEMM (bf16 in; BN1 finalize+apply+relu; dinv-scaled out) --
    gemm2_kernel<<<nblkG, 256, 0, stream>>>(agg_bf, W2, parts, gamma1, beta1,
                                            dinv, h_bf, N, invN);
    // ---- layer 2 gather (+BN2 stats; bf16 agg out, reuses agg_bf) ----
    gather_agg_kernel<<<nblkA, 256, 0, stream>>>(h_bf, rptrR, csr, dinv,
                                                 b2, agg_bf,
                                                 parts + BN_REPS * 128, N);
    // ---- BN2 finalize + residual + relu ----
    final_out_kernel<<<nblkQ, 256, 0, stream>>>(agg_bf, parts + BN_REPS * 128,
                                                gamma2, beta2, x, out,
                                                N * 16, invN);
}